// Round 3
// baseline (280.001 us; speedup 1.0000x reference)
//
#include <hip/hip_runtime.h>

// out[i]        = p[i]                      i in [0, SIZE)
// out[SIZE + i] = w[i] * selu(p[i]) + q[i]
//
// Memory-bound (320 MB). Round-1 at 95 us was latency/ILP-limited: 1 float4
// per stream per thread. Fix: block-strided x4 unroll -> 12 outstanding
// 16B loads per thread, non-temporal stores so output doesn't evict inputs
// from L2/L3. Uses clang ext_vector_type (the HIP float4 struct is rejected
// by __builtin_nontemporal_store).

typedef float v4f __attribute__((ext_vector_type(4)));

#define UNROLL 4

__global__ void __launch_bounds__(256)
activation_moduleA_48112223650431_kernel(const v4f* __restrict__ x4,
                                         const v4f* __restrict__ w4,
                                         v4f* __restrict__ out4,
                                         int n4 /* = SIZE/4 */) {
    const float scale = 1.0507009873554805f;
    const float alpha = 1.6732632423543773f;

    int idx = blockIdx.x * (blockDim.x * UNROLL) + threadIdx.x;

    if (idx + (UNROLL - 1) * 256 < n4) {
        // fast path: all UNROLL slots in range (always true for SIZE=16M)
        v4f p[UNROLL], q[UNROLL], w[UNROLL];
#pragma unroll
        for (int u = 0; u < UNROLL; ++u) p[u] = x4[idx + u * 256];
#pragma unroll
        for (int u = 0; u < UNROLL; ++u) q[u] = x4[n4 + idx + u * 256];
#pragma unroll
        for (int u = 0; u < UNROLL; ++u) w[u] = w4[idx + u * 256];

#pragma unroll
        for (int u = 0; u < UNROLL; ++u) {
            v4f r;
#pragma unroll
            for (int c = 0; c < 4; ++c) {
                float pv = p[u][c];
                float s = pv > 0.f ? pv : alpha * (__expf(pv) - 1.f);
                r[c] = w[u][c] * (scale * s) + q[u][c];
            }
            __builtin_nontemporal_store(p[u], &out4[idx + u * 256]);
            __builtin_nontemporal_store(r, &out4[n4 + idx + u * 256]);
        }
    } else {
        // tail (unused at this problem size, kept for safety)
        for (int u = 0; u < UNROLL; ++u) {
            int i = idx + u * 256;
            if (i >= n4) break;
            v4f p = x4[i];
            v4f q = x4[n4 + i];
            v4f w = w4[i];
            v4f r;
#pragma unroll
            for (int c = 0; c < 4; ++c) {
                float pv = p[c];
                float s = pv > 0.f ? pv : alpha * (__expf(pv) - 1.f);
                r[c] = w[c] * (scale * s) + q[c];
            }
            __builtin_nontemporal_store(p, &out4[i]);
            __builtin_nontemporal_store(r, &out4[n4 + i]);
        }
    }
}

extern "C" void kernel_launch(void* const* d_in, const int* in_sizes, int n_in,
                              void* d_out, int out_size, void* d_ws, size_t ws_size,
                              hipStream_t stream) {
    const v4f* x4 = (const v4f*)d_in[0];
    const v4f* w4 = (const v4f*)d_in[1];
    v4f* out4 = (v4f*)d_out;

    int size = in_sizes[1];      // SIZE = N/2 = 16777216
    int n4 = size / 4;           // 4194304 float4 per half

    int block = 256;
    int per_block = block * UNROLL;                 // 1024 float4 per block
    int grid = (n4 + per_block - 1) / per_block;    // 4096 blocks
    activation_moduleA_48112223650431_kernel<<<grid, block, 0, stream>>>(x4, w4, out4, n4);
}

// Round 4
// 267.956 us; speedup vs baseline: 1.0449x; 1.0449x over previous
//
#include <hip/hip_runtime.h>

// out[i]        = p[i]                      i in [0, SIZE)
// out[SIZE + i] = w[i] * selu(p[i]) + q[i]
//
// Round-3 analysis: the fused kernel drives 5 phase-locked streams and
// plateaus at ~3.4 TB/s aggregate. Split into two dispatches:
//   k1: 2-stream copy (m13 shape, ~6.3 TB/s expected)
//   k2: 4-stream selu-residual; p re-read should hit L3 (warmed by k1)
// Both kernels: thread-per-float4, no unroll, no nt hints (round-3 showed
// those neutral-to-negative).

typedef float v4f __attribute__((ext_vector_type(4)));

__global__ void __launch_bounds__(256)
copy_half_kernel(const v4f* __restrict__ x4, v4f* __restrict__ out4, int n4) {
    int i = blockIdx.x * blockDim.x + threadIdx.x;
    if (i < n4) out4[i] = x4[i];
}

__global__ void __launch_bounds__(256)
selu_residual_kernel(const v4f* __restrict__ x4, const v4f* __restrict__ w4,
                     v4f* __restrict__ out4, int n4) {
    int i = blockIdx.x * blockDim.x + threadIdx.x;
    if (i >= n4) return;

    const float scale = 1.0507009873554805f;
    const float alpha = 1.6732632423543773f;

    v4f p = x4[i];        // likely L3-hit (warmed by copy kernel)
    v4f q = x4[n4 + i];
    v4f w = w4[i];

    v4f r;
#pragma unroll
    for (int c = 0; c < 4; ++c) {
        float pv = p[c];
        float s = pv > 0.f ? pv : alpha * (__expf(pv) - 1.f);
        r[c] = w[c] * (scale * s) + q[c];
    }
    out4[n4 + i] = r;
}

extern "C" void kernel_launch(void* const* d_in, const int* in_sizes, int n_in,
                              void* d_out, int out_size, void* d_ws, size_t ws_size,
                              hipStream_t stream) {
    const v4f* x4 = (const v4f*)d_in[0];
    const v4f* w4 = (const v4f*)d_in[1];
    v4f* out4 = (v4f*)d_out;

    int size = in_sizes[1];      // SIZE = N/2 = 16777216
    int n4 = size / 4;           // 4194304 float4 per half

    int block = 256;
    int grid = (n4 + block - 1) / block;   // 16384 blocks

    copy_half_kernel<<<grid, block, 0, stream>>>(x4, out4, n4);
    selu_residual_kernel<<<grid, block, 0, stream>>>(x4, w4, out4, n4);
}